// Round 8
// baseline (18.648 us; speedup 1.0000x reference)
//
#include <hip/hip_runtime.h>

namespace {
constexpr int B = 8, T = 12, N = 325, C = 32, K = 100;
constexpr int KPAD = 36;                      // 16B-aligned rows
constexpr int NPB = 2;                        // nodes per block
constexpr int NPAIRS = (N + NPB - 1) / NPB;   // 163
constexpr float EPSF = 1e-5f;
constexpr float MIN_NORM = 1e-15f;
}

__global__ __launch_bounds__(256) void hcd_kernel(
    const float* __restrict__ x_g,       // [B,T,N,C]
    const float* __restrict__ cw,        // [K,C]
    const float* __restrict__ cptr,      // [1]
    float* __restrict__ out0,            // [B,N,K]
    float* __restrict__ out1)            // [B,T,N,K]
{
  __shared__ float yl[K][KPAD];
  __shared__ float y2l[K];
  __shared__ float x2l[NPB][T];

  const int tid = threadIdx.x;
  const int b  = blockIdx.x / NPAIRS;
  const int np = blockIdx.x % NPAIRS;
  const int n0 = np * NPB;
  const float c  = cptr[0];
  const float sc = sqrtf(c);
  const float inv_c4 = 4.f / c;                 // (2/sqrt(c))^2
  const float HLN2 = 0.34657359028f;            // ln2/2
  const float TLOG2E = 2.88539008178f;          // 2*log2(e)

  // ---- waves 0-1: expmap0(centroids) -> LDS ----
  if (tid < K) {
    float u[C];
    float u2 = 0.f;
    #pragma unroll
    for (int q = 0; q < C / 4; ++q) {
      float4 v = *(const float4*)(cw + tid * C + 4 * q);
      u[4*q+0] = v.x; u[4*q+1] = v.y; u[4*q+2] = v.z; u[4*q+3] = v.w;
    }
    #pragma unroll
    for (int i = 0; i < C; ++i) u2 = fmaf(u[i], u[i], u2);
    float z = sc * fmaxf(sqrtf(u2), MIN_NORM);
    float E  = exp2f(z * TLOG2E);                       // e^(2z)
    float th = (E - 1.f) * __builtin_amdgcn_rcpf(E + 1.f);
    float f  = th * __builtin_amdgcn_rcpf(z);
    #pragma unroll
    for (int q = 0; q < C / 4; ++q) {
      float4 v = make_float4(f*u[4*q+0], f*u[4*q+1], f*u[4*q+2], f*u[4*q+3]);
      *(float4*)&yl[tid][4 * q] = v;
    }
    y2l[tid] = f * f * u2;
  }

  // ---- wave 2: x squared norms (runs concurrently with y-stage) ----
  if (tid >= 128 && tid < 128 + NPB * T) {
    int i  = tid - 128;
    int nl = i / T, t = i - nl * T;
    int n  = n0 + nl;
    if (n < N) {
      const float* xr = x_g + ((size_t)(b * T + t) * N + n) * C;
      float s = 0.f;
      #pragma unroll
      for (int q = 0; q < C / 4; ++q) {
        float4 v = *(const float4*)(xr + 4 * q);
        s = fmaf(v.x, v.x, s); s = fmaf(v.y, v.y, s);
        s = fmaf(v.z, v.z, s); s = fmaf(v.w, v.w, s);
      }
      x2l[nl][t] = s;
    }
  }
  __syncthreads();

  // ---- main: grp wave-uniform; x via SGPR broadcast loads ----
  const int grp = tid >> 7;             // 0..1, uniform per wave
  const int k   = tid & 127;
  const int n   = n0 + grp;
  if (n < N) {                          // wave-uniform guard
    const int kc = (k < K) ? k : (K - 1);   // clamp; extra lanes duplicate k=99

    float yk[C];
    #pragma unroll
    for (int q = 0; q < C / 4; ++q) {
      float4 v = *(const float4*)&yl[kc][4 * q];
      yk[4*q+0] = v.x; yk[4*q+1] = v.y; yk[4*q+2] = v.z; yk[4*q+3] = v.w;
    }
    const float y2 = y2l[kc];
    const float c2 = c * c;
    const float tc = 2.f * c;

    // uniform x-row base (t = 0)
    int rowbase = ((b * T) * N + n) * C;
    rowbase = __builtin_amdgcn_readfirstlane(rowbase);

    float ssum = 0.f;
    #pragma unroll
    for (int t = 0; t < T; ++t) {
      const float* xr = x_g + rowbase + t * (N * C);   // uniform -> s_load
      float a0 = 0.f, a1 = 0.f, a2 = 0.f, a3 = 0.f;
      #pragma unroll
      for (int j = 0; j < C; j += 4) {
        a0 = fmaf(xr[j+0], yk[j+0], a0);
        a1 = fmaf(xr[j+1], yk[j+1], a1);
        a2 = fmaf(xr[j+2], yk[j+2], a2);
        a3 = fmaf(xr[j+3], yk[j+3], a3);
      }
      const float dot = (a0 + a1) + (a2 + a3);

      const float x2 = x2l[grp][t];
      const float xy = -dot;                             // dot(-x, y)
      const float A  = fmaf(tc, xy, 1.f) + c * y2;       // 1 + 2c*xy + c*y2
      const float Bc = 1.f - c * x2;                     // 1 - c*x2
      float num2 = A * A * x2 + Bc * Bc * y2 + 2.f * A * Bc * xy;
      num2 = fmaxf(num2, 0.f);
      float den = fmaf(c2 * x2, y2, fmaf(tc, xy, 1.f));
      den = fmaxf(den, MIN_NORM);
      float s_ = sc * __builtin_amdgcn_sqrtf(num2);
      s_ = fminf(s_, (1.f - EPSF) * den);                // z <= 1-eps
      float r  = (den + s_) * __builtin_amdgcn_rcpf(den - s_);
      float at = HLN2 * __builtin_amdgcn_logf(r);        // atanh(z)
      float d2 = inv_c4 * at * at;
      ssum += d2;
      if (k < K)
        out1[(((size_t)(b * T + t)) * N + n) * K + k] = d2;
    }
    if (k < K)
      out0[((size_t)b * N + n) * K + k] = ssum * (1.f / (float)N);
  }
}

extern "C" void kernel_launch(void* const* d_in, const int* in_sizes, int n_in,
                              void* d_out, int out_size, void* d_ws, size_t ws_size,
                              hipStream_t stream) {
  // identify inputs by size (order-proof): node 998400, centroids 3200, c 1
  const void* xp = nullptr; const void* cwp = nullptr; const void* cp = nullptr;
  for (int i = 0; i < n_in; ++i) {
    if (in_sizes[i] == B * T * N * C)      xp  = d_in[i];
    else if (in_sizes[i] == K * C)         cwp = d_in[i];
    else if (in_sizes[i] == 1)             cp  = d_in[i];
  }
  if (!xp)  xp  = d_in[0];
  if (!cwp) cwp = d_in[1];
  if (!cp)  cp  = d_in[n_in - 1];

  float* out0 = (float*)d_out;                 // [B,N,K]
  float* out1 = out0 + (size_t)B * N * K;      // [B,T,N,K]

  hipLaunchKernelGGL(hcd_kernel, dim3(B * NPAIRS), dim3(256), 0, stream,
                     (const float*)xp, (const float*)cwp, (const float*)cp,
                     out0, out1);
}